// Round 1
// baseline (88.947 us; speedup 1.0000x reference)
//
#include <hip/hip_runtime.h>
#include <math.h>

// Problem constants (fixed by reference setup_inputs)
#define B 8
#define C 256
#define CR 64
#define H 128
#define W 128
#define HW (H*W)              // 16384 = 2^14
#define NELEM (B*C*HW)        // 33554432 = 2^25
#define N4 (NELEM/4)          // 8388608

__device__ __forceinline__ float sigmoidf_(float z) {
    return 1.0f / (1.0f + expf(-z));
}

// ---------------------------------------------------------------------------
// Kernel A: one block, 256 threads. Computes t=(B,C), channel_weight cw=(B,C),
// avg[b], max[b]. All tiny math.
// ---------------------------------------------------------------------------
__global__ __launch_bounds__(256)
void setup_kernel(const float* __restrict__ tf,   // (B,C)
                  const float* __restrict__ pw,   // (C,C) row-major [o][c]
                  const float* __restrict__ pb,   // (C,)
                  const float* __restrict__ g,    // bn_gamma
                  const float* __restrict__ be,   // bn_beta
                  const float* __restrict__ mu,   // bn_mean
                  const float* __restrict__ var,  // bn_var
                  const float* __restrict__ w1,   // (CR,C)
                  const float* __restrict__ b1,   // (CR,)
                  const float* __restrict__ w2,   // (C,CR)
                  const float* __restrict__ b2,   // (C,)
                  float* __restrict__ cw,         // out (B,C)
                  float* __restrict__ avg_out,    // out (B,)
                  float* __restrict__ max_out)    // out (B,)
{
    __shared__ float tf_sh[B][C];
    __shared__ float t_sh[B][C];
    __shared__ float h_sh[B][CR];
    __shared__ float red[16];

    const int tid = threadIdx.x;

    for (int i = tid; i < B * C; i += 256) tf_sh[i / C][i % C] = tf[i];
    __syncthreads();

    // ---- t[b][c] = relu(BN(proj_w[c,:]·tf[b,:] + pb[c])) ----
    const int c = tid;
    float acc[B];
    #pragma unroll
    for (int b = 0; b < B; ++b) acc[b] = 0.0f;
    for (int k = 0; k < C; k += 4) {
        const float4 wv = *reinterpret_cast<const float4*>(pw + c * C + k);
        #pragma unroll
        for (int b = 0; b < B; ++b) {
            acc[b] += wv.x * tf_sh[b][k]     + wv.y * tf_sh[b][k + 1]
                    + wv.z * tf_sh[b][k + 2] + wv.w * tf_sh[b][k + 3];
        }
    }
    {
        const float scale = g[c] * rsqrtf(var[c] + 1e-5f);
        const float bias  = pb[c];
        const float mean  = mu[c];
        const float beta  = be[c];
        #pragma unroll
        for (int b = 0; b < B; ++b) {
            float t = (acc[b] + bias - mean) * scale + beta;
            t_sh[b][c] = fmaxf(t, 0.0f);
        }
    }
    __syncthreads();

    // ---- per-batch sum / max over C ----
    const int lane = tid & 63;
    const int wv_  = tid >> 6;   // wave id, 0..3
    for (int b = 0; b < B; ++b) {
        float v = t_sh[b][tid];
        float s = v, m = v;
        #pragma unroll
        for (int off = 32; off > 0; off >>= 1) {
            s += __shfl_down(s, off);
            m  = fmaxf(m, __shfl_down(m, off));
        }
        if (lane == 0) { red[wv_] = s; red[4 + wv_] = m; }
        __syncthreads();
        if (tid == 0) {
            float ss = red[0] + red[1] + red[2] + red[3];
            float mm = fmaxf(fmaxf(red[4], red[5]), fmaxf(red[6], red[7]));
            avg_out[b] = ss * (1.0f / C);
            max_out[b] = mm;
        }
        __syncthreads();
    }

    // ---- h[b][r] = relu(ca_w1[r,:]·t[b,:] + b1[r]) ----
    {
        const int r   = tid & 63;
        const int grp = tid >> 6;      // 4 groups, each handles 2 batches
        for (int b = grp; b < B; b += 4) {
            float a = b1[r];
            for (int k = 0; k < C; k += 4) {
                const float4 ww = *reinterpret_cast<const float4*>(w1 + r * C + k);
                a += ww.x * t_sh[b][k]     + ww.y * t_sh[b][k + 1]
                   + ww.z * t_sh[b][k + 2] + ww.w * t_sh[b][k + 3];
            }
            h_sh[b][r] = fmaxf(a, 0.0f);
        }
    }
    __syncthreads();

    // ---- cw[b][c] = sigmoid(ca_w2[c,:]·h[b,:] + b2[c]) ----
    {
        const float bias2 = b2[c];
        for (int b = 0; b < B; ++b) {
            float a = bias2;
            for (int r = 0; r < CR; r += 4) {
                const float4 ww = *reinterpret_cast<const float4*>(w2 + c * CR + r);
                a += ww.x * h_sh[b][r]     + ww.y * h_sh[b][r + 1]
                   + ww.z * h_sh[b][r + 2] + ww.w * h_sh[b][r + 3];
            }
            cw[b * C + c] = sigmoidf_(a);
        }
    }
}

// ---------------------------------------------------------------------------
// Kernel B: spatial-weight map sw[b,y,x] = sigmoid(avg[b]*S0 + max[b]*S1 + sb)
// S0/S1 = sums of in-bounds 7x7 taps (input maps are spatially constant).
// 131072 threads, ~100 FLOP each.
// ---------------------------------------------------------------------------
__global__ __launch_bounds__(256)
void swmap_kernel(const float* __restrict__ saw,   // (1,2,7,7) flat
                  const float* __restrict__ sab,   // (1,)
                  const float* __restrict__ avgv,  // (B,)
                  const float* __restrict__ maxv,  // (B,)
                  float* __restrict__ swm)         // out (B,H,W)
{
    const int idx = blockIdx.x * 256 + threadIdx.x;   // < B*HW
    const int b = idx >> 14;
    const int s = idx & (HW - 1);
    const int y = s >> 7;
    const int x = s & (W - 1);
    // valid tap range: iy = y + ky - 3 in [0,H-1]  ->  ky in [3-y, H+2-y]
    const int ky0 = max(0, 3 - y), ky1 = min(6, H + 2 - y);
    const int kx0 = max(0, 3 - x), kx1 = min(6, W + 2 - x);
    float S0 = 0.0f, S1 = 0.0f;
    for (int ky = ky0; ky <= ky1; ++ky) {
        for (int kx = kx0; kx <= kx1; ++kx) {
            S0 += saw[ky * 7 + kx];
            S1 += saw[49 + ky * 7 + kx];
        }
    }
    const float z = avgv[b] * S0 + maxv[b] * S1 + sab[0];
    swm[idx] = sigmoidf_(z);
}

// ---------------------------------------------------------------------------
// Kernel C: out = x * cw[b,c] * sw[b,y,x], float4 grid-stride. Memory-bound.
// ---------------------------------------------------------------------------
__global__ __launch_bounds__(256)
void fuse_kernel(const float4* __restrict__ x4,
                 const float*  __restrict__ cw,    // (B,C)
                 const float4* __restrict__ sw4,   // (B,HW/4)
                 float4* __restrict__ out4)
{
    const int stride = gridDim.x * blockDim.x;
    for (int j = blockIdx.x * blockDim.x + threadIdx.x; j < N4; j += stride) {
        const int s4 = j & 4095;          // HW/4 = 4096
        const int c  = (j >> 12) & 255;
        const int b  = j >> 20;           // C*HW/4 = 2^20
        const float cwv = cw[(b << 8) + c];
        const float4 xs  = x4[j];
        const float4 sws = sw4[(b << 12) + s4];
        float4 o;
        o.x = xs.x * cwv * sws.x;
        o.y = xs.y * cwv * sws.y;
        o.z = xs.z * cwv * sws.z;
        o.w = xs.w * cwv * sws.w;
        out4[j] = o;
    }
}

// ---------------------------------------------------------------------------
extern "C" void kernel_launch(void* const* d_in, const int* in_sizes, int n_in,
                              void* d_out, int out_size, void* d_ws, size_t ws_size,
                              hipStream_t stream) {
    const float* x    = (const float*)d_in[0];
    const float* tf   = (const float*)d_in[1];
    const float* pw   = (const float*)d_in[2];
    const float* pb   = (const float*)d_in[3];
    const float* g    = (const float*)d_in[4];
    const float* be   = (const float*)d_in[5];
    const float* mu   = (const float*)d_in[6];
    const float* var  = (const float*)d_in[7];
    const float* w1   = (const float*)d_in[8];
    const float* b1   = (const float*)d_in[9];
    const float* w2   = (const float*)d_in[10];
    const float* b2   = (const float*)d_in[11];
    const float* saw  = (const float*)d_in[12];
    const float* sab  = (const float*)d_in[13];
    float* out = (float*)d_out;

    // workspace layout (floats): cw[2048] | avg[8] | max[8] | sw[131072]
    float* wsf   = (float*)d_ws;
    float* cw    = wsf;
    float* avgv  = wsf + 2048;
    float* maxv  = wsf + 2056;
    float* swm   = wsf + 2064;   // byte offset 8256, 16B-aligned

    setup_kernel<<<1, 256, 0, stream>>>(tf, pw, pb, g, be, mu, var,
                                        w1, b1, w2, b2, cw, avgv, maxv);
    swmap_kernel<<<(B * HW) / 256, 256, 0, stream>>>(saw, sab, avgv, maxv, swm);
    fuse_kernel<<<2048, 256, 0, stream>>>((const float4*)x, cw,
                                          (const float4*)swm, (float4*)out);
}